// Round 2
// baseline (737.485 us; speedup 1.0000x reference)
//
#include <hip/hip_runtime.h>

// SpatialEncoding: out[b,n1,n2] = weight[path_distance_map[b,e]] for the
// LAST e with edge_index_map[b,e]=(n1,n2); else weight[511].
//
// Strategy (round 2): avoid device-scope atomics to the 256MB output
// (write-through 32B/atomic -> ~1TB/s random ceiling, 486us). Instead:
//   P0: zero 256KB per-(b,row) counters in d_ws
//   P1: bucket edges by (b, n1) into d_out itself (int2 records, cap 512/row)
//   P2: per 8-row block: LDS atomicMax resolve (last-e-wins), decode via
//       LDS weight table, coalesced float4 output store.
// Record order within a bucket is nondeterministic, but the resolve max is
// order-independent -> deterministic output across graph replays.

#define BB 64
#define TT 1024
#define EE 200000
#define MAXD 512
#define CAP 512   // int2 records per (b,row) bucket == 1024 ints == one out row
#define GR 8      // rows per resolve block

// ---- bucketed path ----

__global__ void __launch_bounds__(256)
bucket_kernel(const int* __restrict__ pdm,
              const int* __restrict__ eim,
              int* __restrict__ cnt,
              int2* __restrict__ recs) {
    int e = blockIdx.x * 256 + threadIdx.x;
    int b = blockIdx.y;
    if (e >= EE) return;
    int d = pdm[(size_t)b * EE + e];
    int2 n = ((const int2*)eim)[(size_t)b * EE + e];   // (n1, n2)
    int bucket = b * TT + n.x;
    int pos = atomicAdd(&cnt[bucket], 1);
    if (pos < CAP)   // P(overflow) ~ 0: bucket load is Poisson(195), cap 512
        recs[(size_t)bucket * CAP + pos] = make_int2(n.y, (e << 9) | d);
}

__global__ void __launch_bounds__(256)
resolve_kernel(const float* __restrict__ w,
               const int* __restrict__ cnt,
               float* __restrict__ out) {
    __shared__ int tile[GR * TT];      // 32 KB
    __shared__ float sw[MAXD];         // 2 KB
    int b  = blockIdx.y;
    int r0 = blockIdx.x * GR;
    for (int i = threadIdx.x; i < MAXD; i += 256) sw[i] = w[i];
    for (int i = threadIdx.x; i < GR * TT; i += 256) tile[i] = -1;
    __syncthreads();

    const int2* recs = (const int2*)out;
    for (int lr = 0; lr < GR; ++lr) {
        int bucket = b * TT + r0 + lr;
        int c = cnt[bucket];
        c = c < CAP ? c : CAP;
        for (int i = threadIdx.x; i < c; i += 256) {
            int2 rec = recs[(size_t)bucket * CAP + i];
            atomicMax(&tile[lr * TT + rec.x], rec.y);
        }
    }
    __syncthreads();

    // overwrite these same 8 rows with final floats (reads above are done)
    float4* o4 = (float4*)(out + ((size_t)b * TT + r0) * TT);
    const int4* t4 = (const int4*)tile;
    for (int i = threadIdx.x; i < GR * TT / 4; i += 256) {
        int4 v = t4[i];
        float4 r;
        r.x = sw[v.x < 0 ? (MAXD - 1) : (v.x & (MAXD - 1))];
        r.y = sw[v.y < 0 ? (MAXD - 1) : (v.y & (MAXD - 1))];
        r.z = sw[v.z < 0 ? (MAXD - 1) : (v.z & (MAXD - 1))];
        r.w = sw[v.w < 0 ? (MAXD - 1) : (v.w & (MAXD - 1))];
        o4[i] = r;
    }
}

// ---- fallback path (round-1 algorithm) if d_ws is too small ----

__global__ void __launch_bounds__(256)
scatter_max_kernel(const int* __restrict__ pdm,
                   const int* __restrict__ eim,
                   int* __restrict__ outi) {
    int e = blockIdx.x * blockDim.x + threadIdx.x;
    int b = blockIdx.y;
    if (e >= EE) return;
    int d = pdm[(size_t)b * EE + e];
    int2 n = ((const int2*)eim)[(size_t)b * EE + e];
    int packed = (e << 9) | d;
    atomicMax(&outi[((size_t)b * TT + (size_t)n.x) * TT + (size_t)n.y], packed);
}

__global__ void __launch_bounds__(256)
finalize_kernel(const float* __restrict__ w, float* __restrict__ out, size_t n4) {
    __shared__ float sw[MAXD];
    for (int i = threadIdx.x; i < MAXD; i += blockDim.x) sw[i] = w[i];
    __syncthreads();
    const size_t stride = (size_t)gridDim.x * blockDim.x;
    int4* pi = (int4*)out;
    float4* pf = (float4*)out;
    for (size_t i = (size_t)blockIdx.x * blockDim.x + threadIdx.x; i < n4; i += stride) {
        int4 v = pi[i];
        float4 r;
        r.x = sw[v.x < 0 ? (MAXD - 1) : (v.x & (MAXD - 1))];
        r.y = sw[v.y < 0 ? (MAXD - 1) : (v.y & (MAXD - 1))];
        r.z = sw[v.z < 0 ? (MAXD - 1) : (v.z & (MAXD - 1))];
        r.w = sw[v.w < 0 ? (MAXD - 1) : (v.w & (MAXD - 1))];
        pf[i] = r;
    }
}

extern "C" void kernel_launch(void* const* d_in, const int* in_sizes, int n_in,
                              void* d_out, int out_size, void* d_ws, size_t ws_size,
                              hipStream_t stream) {
    const float* w   = (const float*)d_in[1];
    const int*   pdm = (const int*)d_in[2];
    const int*   eim = (const int*)d_in[3];
    float* out = (float*)d_out;

    const size_t cnt_bytes = (size_t)BB * TT * sizeof(int);   // 256 KB

    if (ws_size >= cnt_bytes) {
        // P0: zero counters
        hipMemsetAsync(d_ws, 0, cnt_bytes, stream);
        // P1: bucket edges into d_out (as int2 records)
        dim3 bgrid((EE + 255) / 256, BB);
        bucket_kernel<<<bgrid, 256, 0, stream>>>(pdm, eim, (int*)d_ws, (int2*)d_out);
        // P2: per-8-row LDS resolve + coalesced final store
        dim3 rgrid(TT / GR, BB);
        resolve_kernel<<<rgrid, 256, 0, stream>>>(w, (const int*)d_ws, out);
    } else {
        // fallback: round-1 atomic path
        hipMemsetAsync(d_out, 0xFF, (size_t)out_size * sizeof(float), stream);
        dim3 sgrid((EE + 255) / 256, BB);
        scatter_max_kernel<<<sgrid, 256, 0, stream>>>(pdm, eim, (int*)d_out);
        size_t n4 = (size_t)out_size / 4;
        finalize_kernel<<<2048, 256, 0, stream>>>(w, out, n4);
    }
}

// Round 3
// 131.964 us; speedup vs baseline: 5.5885x; 5.5885x over previous
//
#include <hip/hip_runtime.h>

// SpatialEncoding: out[b,n1,n2] = weight[path_distance_map[b,e]] for the
// LAST e with edge_index_map[b,e]=(n1,n2); else weight[511].
//
// Round 3: block-aggregated binning (64 coarse buckets of 16 rows per batch)
// + per-bucket LDS resolve. Fixes round 2's two failures:
//  - per-edge global atomicAdd (return-latency on hot counters) -> one
//    atomicAdd per (block,bucket): 401k atomics instead of 12.8M
//  - random 8B record writes (32B-granule, 513MB) -> LDS reorder by bucket,
//    copy-out in contiguous ~32-record runs (~110MB)
// Records for coarse bucket q are stored in the SAME 64KB region of d_out
// that resolve block q later overwrites -> no scratch, no cross-block hazard.
// Last-write-wins via max over packed (e<<9|d): order-independent ->
// deterministic across graph replays despite nondeterministic binning order.

#define BB 64
#define TT 1024
#define EE 200000
#define MAXD 512
#define GRP 16              // rows per coarse bucket (resolve tile height)
#define NG  (TT / GRP)      // 64 coarse buckets per batch
#define CAP2 8192           // records per bucket region (== 64KB of int2)
#define CPB 2048            // edges per bin block
#define EPT 8               // edges per thread (256 threads)

__global__ void __launch_bounds__(256)
bin_kernel(const int* __restrict__ pdm,
           const int* __restrict__ eim,
           int* __restrict__ gcnt,       // [BB*NG] global bucket counters
           int2* __restrict__ grecs) {   // d_out viewed as record slots
    __shared__ int hist[NG], prefix[NG], resv[NG];
    __shared__ int2 rec[CPB];
    __shared__ int dst[CPB];
    const int tid = threadIdx.x;
    const int b = blockIdx.y;
    const int e0 = blockIdx.x * CPB + tid * EPT;

    if (tid < NG) hist[tid] = 0;
    __syncthreads();

    // ---- load 8 contiguous edges per thread (vectorized int4) ----
    int dvals[EPT]; int2 nvals[EPT]; int nv;
    const int* pb = pdm + (size_t)b * EE;
    const int2* ebp = ((const int2*)eim) + (size_t)b * EE;
    if (e0 + EPT <= EE) {
        const int4* p4 = (const int4*)(pb + e0);
        int4 pA = p4[0], pB = p4[1];
        dvals[0]=pA.x; dvals[1]=pA.y; dvals[2]=pA.z; dvals[3]=pA.w;
        dvals[4]=pB.x; dvals[5]=pB.y; dvals[6]=pB.z; dvals[7]=pB.w;
        const int4* e4 = (const int4*)(ebp + e0);
        int4 eA=e4[0], eB=e4[1], eC=e4[2], eD=e4[3];
        nvals[0]=make_int2(eA.x,eA.y); nvals[1]=make_int2(eA.z,eA.w);
        nvals[2]=make_int2(eB.x,eB.y); nvals[3]=make_int2(eB.z,eB.w);
        nvals[4]=make_int2(eC.x,eC.y); nvals[5]=make_int2(eC.z,eC.w);
        nvals[6]=make_int2(eD.x,eD.y); nvals[7]=make_int2(eD.z,eD.w);
        nv = EPT;
    } else {
        nv = EE - e0; if (nv < 0) nv = 0; if (nv > EPT) nv = EPT;
        #pragma unroll
        for (int k = 0; k < EPT; ++k)
            if (k < nv) { dvals[k] = pb[e0 + k]; nvals[k] = ebp[e0 + k]; }
    }

    // ---- LDS histogram; per-edge rank within (block,bucket) ----
    int g[EPT], rk[EPT];
    #pragma unroll
    for (int k = 0; k < EPT; ++k) {
        if (k < nv) {
            g[k] = nvals[k].x >> 4;
            rk[k] = atomicAdd(&hist[g[k]], 1);
        }
    }
    __syncthreads();

    // ---- wave-parallel exclusive scan + ONE global reserve per bucket ----
    if (tid < NG) {
        int v = hist[tid], inc = v;
        #pragma unroll
        for (int off = 1; off < NG; off <<= 1) {
            int t = __shfl_up(inc, off);
            if (tid >= off) inc += t;
        }
        prefix[tid] = inc - v;
        resv[tid] = atomicAdd(&gcnt[b * NG + tid], v);
    }
    __syncthreads();

    // ---- reorder records by bucket in LDS; precompute global slots ----
    #pragma unroll
    for (int k = 0; k < EPT; ++k) {
        if (k < nv) {
            int e = e0 + k;
            int lp = prefix[g[k]] + rk[k];
            rec[lp] = make_int2(((nvals[k].x & (GRP - 1)) << 10) | nvals[k].y,
                                (e << 9) | dvals[k]);
            int gp = resv[g[k]] + rk[k];
            dst[lp] = (gp < CAP2) ? (((b * NG + g[k]) << 13) | gp) : -1;
        }
    }
    __syncthreads();

    // ---- copy out: bucket-ordered -> contiguous runs, good coalescing ----
    int total = EE - blockIdx.x * CPB;
    if (total > CPB) total = CPB;
    for (int j = tid; j < total; j += 256) {
        int dd = dst[j];
        if (dd >= 0) grecs[dd] = rec[j];
    }
}

__global__ void __launch_bounds__(512)
resolve_kernel(const float* __restrict__ w,
               const int* __restrict__ gcnt,
               float* __restrict__ out) {
    __shared__ int tile[GRP * TT];     // 64 KB exactly
    const int tid = threadIdx.x;
    const int q = blockIdx.x;          // coarse bucket id = b*NG + g

    int4* t4 = (int4*)tile;
    for (int i = tid; i < GRP * TT / 4; i += 512)
        t4[i] = make_int4(-1, -1, -1, -1);
    __syncthreads();

    int c = gcnt[q]; if (c > CAP2) c = CAP2;
    const int2* recs = ((const int2*)out) + ((size_t)q << 13);
    for (int i = tid; i < c; i += 512) {
        int2 r = recs[i];
        atomicMax(&tile[r.x], r.y);    // r.x = (row_in_grp<<10)|n2
    }
    __syncthreads();

    // overwrite this bucket's 64KB output region (record reads are done)
    float4* o4 = (float4*)(out + (size_t)q * (GRP * TT));
    for (int i = tid; i < GRP * TT / 4; i += 512) {
        int4 v = t4[i];
        float4 r;
        r.x = w[v.x < 0 ? (MAXD - 1) : (v.x & (MAXD - 1))];
        r.y = w[v.y < 0 ? (MAXD - 1) : (v.y & (MAXD - 1))];
        r.z = w[v.z < 0 ? (MAXD - 1) : (v.z & (MAXD - 1))];
        r.w = w[v.w < 0 ? (MAXD - 1) : (v.w & (MAXD - 1))];
        o4[i] = r;
    }
}

// ---- fallback (round-1 algorithm) if d_ws is unexpectedly tiny ----

__global__ void __launch_bounds__(256)
scatter_max_kernel(const int* __restrict__ pdm,
                   const int* __restrict__ eim,
                   int* __restrict__ outi) {
    int e = blockIdx.x * blockDim.x + threadIdx.x;
    int b = blockIdx.y;
    if (e >= EE) return;
    int d = pdm[(size_t)b * EE + e];
    int2 n = ((const int2*)eim)[(size_t)b * EE + e];
    atomicMax(&outi[((size_t)b * TT + (size_t)n.x) * TT + (size_t)n.y],
              (e << 9) | d);
}

__global__ void __launch_bounds__(256)
finalize_kernel(const float* __restrict__ w, float* __restrict__ out, size_t n4) {
    const size_t stride = (size_t)gridDim.x * blockDim.x;
    int4* pi = (int4*)out;
    float4* pf = (float4*)out;
    for (size_t i = (size_t)blockIdx.x * blockDim.x + threadIdx.x; i < n4; i += stride) {
        int4 v = pi[i];
        float4 r;
        r.x = w[v.x < 0 ? (MAXD - 1) : (v.x & (MAXD - 1))];
        r.y = w[v.y < 0 ? (MAXD - 1) : (v.y & (MAXD - 1))];
        r.z = w[v.z < 0 ? (MAXD - 1) : (v.z & (MAXD - 1))];
        r.w = w[v.w < 0 ? (MAXD - 1) : (v.w & (MAXD - 1))];
        pf[i] = r;
    }
}

extern "C" void kernel_launch(void* const* d_in, const int* in_sizes, int n_in,
                              void* d_out, int out_size, void* d_ws, size_t ws_size,
                              hipStream_t stream) {
    const float* w   = (const float*)d_in[1];
    const int*   pdm = (const int*)d_in[2];
    const int*   eim = (const int*)d_in[3];
    float* out = (float*)d_out;

    const size_t cnt_bytes = (size_t)BB * NG * sizeof(int);   // 16 KB

    if (ws_size >= cnt_bytes) {
        hipMemsetAsync(d_ws, 0, cnt_bytes, stream);
        dim3 bgrid((EE + CPB - 1) / CPB, BB);                 // (98, 64)
        bin_kernel<<<bgrid, 256, 0, stream>>>(pdm, eim, (int*)d_ws, (int2*)d_out);
        resolve_kernel<<<BB * NG, 512, 0, stream>>>(w, (const int*)d_ws, out);
    } else {
        hipMemsetAsync(d_out, 0xFF, (size_t)out_size * sizeof(float), stream);
        dim3 sgrid((EE + 255) / 256, BB);
        scatter_max_kernel<<<sgrid, 256, 0, stream>>>(pdm, eim, (int*)d_out);
        finalize_kernel<<<2048, 256, 0, stream>>>(w, out, (size_t)out_size / 4);
    }
}

// Round 4
// 123.630 us; speedup vs baseline: 5.9652x; 1.0674x over previous
//
#include <hip/hip_runtime.h>

// SpatialEncoding: out[b,n1,n2] = weight[path_distance_map[b,e]] for the
// LAST e with edge_index_map[b,e]=(n1,n2); else weight[511].
//
// Round 4: round-3 structure (block-aggregated binning + per-bucket LDS
// resolve, records aliased into d_out), tuned:
//  - GRP 16->8: resolve LDS tile 64KB->32KB -> 4 blocks/CU (100% waves,
//    was 50%) to hide record-read + LDS-atomic latency
//  - NG 64->128: bin LDS-histogram contention halves (two-wave scan)
//  - resolve decodes through a 2KB LDS weight table
// Last-write-wins via max over packed (e<<9|d): order-independent ->
// deterministic across graph replays despite nondeterministic bin order.

#define BB 64
#define TT 1024
#define EE 200000
#define MAXD 512
#define GRP 8               // rows per bucket (resolve tile height)
#define NG  (TT / GRP)      // 128 buckets per batch
#define CAPR 4096           // int2 records per bucket region (== 32KB == GRP rows)
#define CPB 2048            // edges per bin block
#define EPT 8               // edges per thread (256 threads)

__global__ void __launch_bounds__(256)
bin_kernel(const int* __restrict__ pdm,
           const int* __restrict__ eim,
           int* __restrict__ gcnt,       // [BB*NG] global bucket counters
           int2* __restrict__ grecs) {   // d_out viewed as record slots
    __shared__ int hist[NG], prefix[NG], resv[NG];
    __shared__ int wsum[2];
    __shared__ int2 rec[CPB];
    __shared__ int dst[CPB];
    const int tid = threadIdx.x;
    const int b = blockIdx.y;
    const int e0 = blockIdx.x * CPB + tid * EPT;

    for (int i = tid; i < NG; i += 256) hist[i] = 0;
    __syncthreads();

    // ---- load 8 contiguous edges per thread (vectorized int4) ----
    int dvals[EPT]; int2 nvals[EPT]; int nv;
    const int* pb = pdm + (size_t)b * EE;
    const int2* ebp = ((const int2*)eim) + (size_t)b * EE;
    if (e0 + EPT <= EE) {
        const int4* p4 = (const int4*)(pb + e0);
        int4 pA = p4[0], pB = p4[1];
        dvals[0]=pA.x; dvals[1]=pA.y; dvals[2]=pA.z; dvals[3]=pA.w;
        dvals[4]=pB.x; dvals[5]=pB.y; dvals[6]=pB.z; dvals[7]=pB.w;
        const int4* e4 = (const int4*)(ebp + e0);
        int4 eA=e4[0], eB=e4[1], eC=e4[2], eD=e4[3];
        nvals[0]=make_int2(eA.x,eA.y); nvals[1]=make_int2(eA.z,eA.w);
        nvals[2]=make_int2(eB.x,eB.y); nvals[3]=make_int2(eB.z,eB.w);
        nvals[4]=make_int2(eC.x,eC.y); nvals[5]=make_int2(eC.z,eC.w);
        nvals[6]=make_int2(eD.x,eD.y); nvals[7]=make_int2(eD.z,eD.w);
        nv = EPT;
    } else {
        nv = EE - e0; if (nv < 0) nv = 0; if (nv > EPT) nv = EPT;
        #pragma unroll
        for (int k = 0; k < EPT; ++k)
            if (k < nv) { dvals[k] = pb[e0 + k]; nvals[k] = ebp[e0 + k]; }
    }

    // ---- LDS histogram; per-edge rank within (block,bucket) ----
    int g[EPT], rk[EPT];
    #pragma unroll
    for (int k = 0; k < EPT; ++k) {
        if (k < nv) {
            g[k] = nvals[k].x >> 3;          // n1 / GRP
            rk[k] = atomicAdd(&hist[g[k]], 1);
        }
    }
    __syncthreads();

    // ---- exclusive scan over NG=128 (two wave64 shuffle scans + fixup)
    //      + ONE global reserve per bucket ----
    if (tid < NG) {
        int v = hist[tid], inc = v;
        #pragma unroll
        for (int off = 1; off < 64; off <<= 1) {
            int t = __shfl_up(inc, off);
            if ((tid & 63) >= off) inc += t;
        }
        if ((tid & 63) == 63) wsum[tid >> 6] = inc;
        prefix[tid] = inc - v;
        resv[tid] = atomicAdd(&gcnt[b * NG + tid], v);
    }
    __syncthreads();
    if (tid >= 64 && tid < NG) prefix[tid] += wsum[0];
    __syncthreads();

    // ---- reorder records by bucket in LDS; precompute global slots ----
    #pragma unroll
    for (int k = 0; k < EPT; ++k) {
        if (k < nv) {
            int e = e0 + k;
            int lp = prefix[g[k]] + rk[k];
            rec[lp] = make_int2(((nvals[k].x & (GRP - 1)) << 10) | nvals[k].y,
                                (e << 9) | dvals[k]);
            int gp = resv[g[k]] + rk[k];
            dst[lp] = (gp < CAPR) ? (((b * NG + g[k]) << 12) | gp) : -1;
        }
    }
    __syncthreads();

    // ---- copy out: bucket-ordered -> contiguous runs, good coalescing ----
    int total = EE - blockIdx.x * CPB;
    if (total > CPB) total = CPB;
    for (int j = tid; j < total; j += 256) {
        int dd = dst[j];
        if (dd >= 0)
            grecs[((size_t)(dd >> 12) << 12) | (dd & (CAPR - 1))] = rec[j];
    }
}

__global__ void __launch_bounds__(512)
resolve_kernel(const float* __restrict__ w,
               const int* __restrict__ gcnt,
               float* __restrict__ out) {
    __shared__ int tile[GRP * TT];     // 32 KB
    __shared__ float sw[MAXD];         // 2 KB
    const int tid = threadIdx.x;
    const int q = blockIdx.x;          // bucket id = b*NG + g

    for (int i = tid; i < MAXD; i += 512) sw[i] = w[i];
    int4* t4 = (int4*)tile;
    for (int i = tid; i < GRP * TT / 4; i += 512)
        t4[i] = make_int4(-1, -1, -1, -1);
    __syncthreads();

    int c = gcnt[q]; if (c > CAPR) c = CAPR;
    const int2* recs = ((const int2*)out) + ((size_t)q * CAPR);
    for (int i = tid; i < c; i += 512) {
        int2 r = recs[i];
        atomicMax(&tile[r.x], r.y);    // r.x = (row_in_grp<<10)|n2
    }
    __syncthreads();

    // overwrite this bucket's 32KB output region (record reads are done)
    float4* o4 = (float4*)(out + (size_t)q * (GRP * TT));
    for (int i = tid; i < GRP * TT / 4; i += 512) {
        int4 v = t4[i];
        float4 r;
        r.x = sw[v.x < 0 ? (MAXD - 1) : (v.x & (MAXD - 1))];
        r.y = sw[v.y < 0 ? (MAXD - 1) : (v.y & (MAXD - 1))];
        r.z = sw[v.z < 0 ? (MAXD - 1) : (v.z & (MAXD - 1))];
        r.w = sw[v.w < 0 ? (MAXD - 1) : (v.w & (MAXD - 1))];
        o4[i] = r;
    }
}

// ---- fallback (round-1 algorithm) if d_ws is unexpectedly tiny ----

__global__ void __launch_bounds__(256)
scatter_max_kernel(const int* __restrict__ pdm,
                   const int* __restrict__ eim,
                   int* __restrict__ outi) {
    int e = blockIdx.x * blockDim.x + threadIdx.x;
    int b = blockIdx.y;
    if (e >= EE) return;
    int d = pdm[(size_t)b * EE + e];
    int2 n = ((const int2*)eim)[(size_t)b * EE + e];
    atomicMax(&outi[((size_t)b * TT + (size_t)n.x) * TT + (size_t)n.y],
              (e << 9) | d);
}

__global__ void __launch_bounds__(256)
finalize_kernel(const float* __restrict__ w, float* __restrict__ out, size_t n4) {
    const size_t stride = (size_t)gridDim.x * blockDim.x;
    int4* pi = (int4*)out;
    float4* pf = (float4*)out;
    for (size_t i = (size_t)blockIdx.x * blockDim.x + threadIdx.x; i < n4; i += stride) {
        int4 v = pi[i];
        float4 r;
        r.x = w[v.x < 0 ? (MAXD - 1) : (v.x & (MAXD - 1))];
        r.y = w[v.y < 0 ? (MAXD - 1) : (v.y & (MAXD - 1))];
        r.z = w[v.z < 0 ? (MAXD - 1) : (v.z & (MAXD - 1))];
        r.w = w[v.w < 0 ? (MAXD - 1) : (v.w & (MAXD - 1))];
        pf[i] = r;
    }
}

extern "C" void kernel_launch(void* const* d_in, const int* in_sizes, int n_in,
                              void* d_out, int out_size, void* d_ws, size_t ws_size,
                              hipStream_t stream) {
    const float* w   = (const float*)d_in[1];
    const int*   pdm = (const int*)d_in[2];
    const int*   eim = (const int*)d_in[3];
    float* out = (float*)d_out;

    const size_t cnt_bytes = (size_t)BB * NG * sizeof(int);   // 32 KB

    if (ws_size >= cnt_bytes) {
        hipMemsetAsync(d_ws, 0, cnt_bytes, stream);
        dim3 bgrid((EE + CPB - 1) / CPB, BB);                 // (98, 64)
        bin_kernel<<<bgrid, 256, 0, stream>>>(pdm, eim, (int*)d_ws, (int2*)d_out);
        resolve_kernel<<<BB * NG, 512, 0, stream>>>(w, (const int*)d_ws, out);
    } else {
        hipMemsetAsync(d_out, 0xFF, (size_t)out_size * sizeof(float), stream);
        dim3 sgrid((EE + 255) / 256, BB);
        scatter_max_kernel<<<sgrid, 256, 0, stream>>>(pdm, eim, (int*)d_out);
        finalize_kernel<<<2048, 256, 0, stream>>>(w, out, (size_t)out_size / 4);
    }
}